// Round 4
// baseline (351.505 us; speedup 1.0000x reference)
//
#include <hip/hip_runtime.h>

typedef float vf4 __attribute__((ext_vector_type(4)));
typedef int   vi4 __attribute__((ext_vector_type(4)));

// LUT layout in d_ws (float): scale s entry a -> 8 floats [pb0,pb1,pb2,v0..v4]
// bases (floats): s0=0, s1=64, s2=576, s3=4672; total 37440 floats = 149,760 B.

__global__ __launch_bounds__(256) void build_lut_kernel(
    const float* __restrict__ pat,   // (4,3,4096)
    const float* __restrict__ pos,   // (4,5,4096)
    const int*   __restrict__ conn,  // (4,5,12)
    float* __restrict__ lut)
{
    int t = blockIdx.x * 256 + threadIdx.x;
    if (t >= 4680) return;
    int s, a, basef;
    if (t < 8)        { s = 0; a = t;       basef = 0; }
    else if (t < 72)  { s = 1; a = t - 8;   basef = 64; }
    else if (t < 584) { s = 2; a = t - 72;  basef = 576; }
    else              { s = 3; a = t - 584; basef = 4672; }
    int n = s + 1;
    int tn = 3 * n;           // ctx bits
    int in_bits = tn + 3;     // ctx + pbits
    int nb = in_bits < 12 ? in_bits : 12;

    // pos_in bit j (j<tn) is paddr bit (tn-1-j); paddr == a
    unsigned posmask = 0;
    for (int j = 0; j < tn; ++j)
        posmask |= (((unsigned)a >> (tn - 1 - j)) & 1u) << j;

    float outv[8];
    for (int j = 0; j < 3; ++j) {
        float v = pat[(s * 3 + j) * 4096 + a];
        unsigned b = (v > 0.5f) ? 1u : 0u;
        outv[j] = (float)b;
        posmask |= b << (tn + j);
    }
    for (int k = 0; k < 5; ++k) {
        unsigned addr = 0;
        for (int j = 0; j < nb; ++j) {
            int c = conn[(s * 5 + k) * 12 + j] % in_bits;
            addr |= ((posmask >> c) & 1u) << j;
        }
        outv[3 + k] = pos[(s * 5 + k) * 4096 + addr];
    }
    vf4* d4 = (vf4*)(lut + basef + a * 8);
    d4[0] = (vf4){outv[0], outv[1], outv[2], outv[3]};
    d4[1] = (vf4){outv[4], outv[5], outv[6], outv[7]};
}

__global__ __launch_bounds__(512) void gather_kernel(
    const vi4* __restrict__ tb4,     // type_bits as int4 (3 per sample)
    const float* __restrict__ lut,
    vf4* __restrict__ out4,          // B*8 float4s
    int nsamp, long long total4)
{
    int t    = threadIdx.x;
    int lane = t & 63;
    int wave = t >> 6;

    // Wave handles 64 consecutive samples; their 192 int4s are loaded as
    // three CONTIGUOUS 64-lane loads (1 KB each, perfectly coalesced).
    long long waveS  = (long long)blockIdx.x * 512 + wave * 64;  // first sample
    long long i4base = waveS * 3;                                // first int4
    long long n4     = (long long)nsamp * 3;

    unsigned m = 0;   // byte k holds the 4-bit nibble of flat int4 (i4base + 64k + lane)
#pragma unroll
    for (int k = 0; k < 3; ++k) {
        long long idx = i4base + k * 64 + lane;
        if (idx < n4) {
            vi4 x = tb4[idx];
            unsigned nib = ((unsigned)x.x << 3) | ((unsigned)x.y << 2) |
                           ((unsigned)x.z << 1) |  (unsigned)x.w;
            m |= nib << (8 * k);
        }
    }

    // Reassemble this lane's sample key: sample i = waveS + lane needs flat
    // int4s 3*lane+j (j=0..2) within the wave window; piece j lives at
    // source lane (3*lane+j)&63, byte (3*lane+j)>>6.
    unsigned P = 0;
#pragma unroll
    for (int j = 0; j < 3; ++j) {
        int f = 3 * lane + j;
        unsigned mm  = (unsigned)__shfl((int)m, f & 63, 64);
        unsigned nib = (mm >> (8 * (f >> 6))) & 0xFu;
        P |= nib << (8 - 4 * j);   // nib0<<8 | nib1<<4 | nib2
    }

    // Per iteration i the wave writes the 8 chunks of 8 samples; P broadcast
    // in-wave via shfl (no LDS, no barrier).
    int s    = (lane & 7) >> 1;
    int half = lane & 1;
    unsigned mask  = (8u << (3 * s)) - 1u;                                  // 2^{3n}-1
    unsigned base4 = (unsigned)((0x0490009000100000ull >> (16 * s)) & 0xFFFFull); // {0,16,144,1168}
    const vf4* lutp = (const vf4*)lut + base4 + half;

    long long outBase = (long long)blockIdx.x * 4096 + wave * 512 + lane;
#pragma unroll
    for (int i = 0; i < 8; ++i) {
        unsigned Ps = (unsigned)__shfl((int)P, i * 8 + (lane >> 3), 64);
        long long g = outBase + (long long)(i * 64);
        if (g < total4) {
            vf4 v = lutp[(Ps & mask) * 2];         // cached: LUT is the only reused data
            __builtin_nontemporal_store(v, &out4[g]);
        }
    }
}

extern "C" void kernel_launch(void* const* d_in, const int* in_sizes, int n_in,
                              void* d_out, int out_size, void* d_ws, size_t ws_size,
                              hipStream_t stream) {
    const int*   type_bits = (const int*)d_in[0];
    const float* pat       = (const float*)d_in[1];
    const float* pos       = (const float*)d_in[2];
    const int*   conn      = (const int*)d_in[3];
    float* lut = (float*)d_ws;   // needs 149,760 B

    int nsamp = in_sizes[0] / 12;                 // 2,000,000
    long long total4 = (long long)out_size / 4;   // 16,000,000 float4s

    build_lut_kernel<<<(4680 + 255) / 256, 256, 0, stream>>>(pat, pos, conn, lut);
    int nblocks = (nsamp + 511) / 512;
    gather_kernel<<<nblocks, 512, 0, stream>>>((const vi4*)type_bits, lut,
                                               (vf4*)d_out, nsamp, total4);
}

// Round 5
// 346.466 us; speedup vs baseline: 1.0145x; 1.0145x over previous
//
#include <hip/hip_runtime.h>

typedef float vf4 __attribute__((ext_vector_type(4)));
typedef int   vi4 __attribute__((ext_vector_type(4)));

// LUT layout in d_ws (float): scale s entry a -> 8 floats [pb0,pb1,pb2,v0..v4]
// bases (floats): s0=0, s1=64, s2=576, s3=4672; total 37440 floats = 149,760 B.

__global__ __launch_bounds__(256) void build_lut_kernel(
    const float* __restrict__ pat,   // (4,3,4096)
    const float* __restrict__ pos,   // (4,5,4096)
    const int*   __restrict__ conn,  // (4,5,12)
    float* __restrict__ lut)
{
    int t = blockIdx.x * 256 + threadIdx.x;
    if (t >= 4680) return;
    int s, a, basef;
    if (t < 8)        { s = 0; a = t;       basef = 0; }
    else if (t < 72)  { s = 1; a = t - 8;   basef = 64; }
    else if (t < 584) { s = 2; a = t - 72;  basef = 576; }
    else              { s = 3; a = t - 584; basef = 4672; }
    int n = s + 1;
    int tn = 3 * n;           // ctx bits
    int in_bits = tn + 3;     // ctx + pbits
    int nb = in_bits < 12 ? in_bits : 12;

    // pos_in bit j (j<tn) is paddr bit (tn-1-j); paddr == a
    unsigned posmask = 0;
    for (int j = 0; j < tn; ++j)
        posmask |= (((unsigned)a >> (tn - 1 - j)) & 1u) << j;

    float outv[8];
    for (int j = 0; j < 3; ++j) {
        float v = pat[(s * 3 + j) * 4096 + a];
        unsigned b = (v > 0.5f) ? 1u : 0u;
        outv[j] = (float)b;
        posmask |= b << (tn + j);
    }
    for (int k = 0; k < 5; ++k) {
        unsigned addr = 0;
        for (int j = 0; j < nb; ++j) {
            int c = conn[(s * 5 + k) * 12 + j] % in_bits;
            addr |= ((posmask >> c) & 1u) << j;
        }
        outv[3 + k] = pos[(s * 5 + k) * 4096 + addr];
    }
    vf4* d4 = (vf4*)(lut + basef + a * 8);
    d4[0] = (vf4){outv[0], outv[1], outv[2], outv[3]};
    d4[1] = (vf4){outv[4], outv[5], outv[6], outv[7]};
}

// Persistent blocks: full LUT staged in LDS (149,760 B, 1 block/CU), so the
// vmem pipe sees ONLY a coalesced input stream + nt output stream (copy-like);
// scattered LUT reads move to the LDS pipe and overlap.
__global__ __launch_bounds__(1024) void gather_kernel(
    const vi4* __restrict__ tb4,     // type_bits as int4 (3 per sample)
    const float* __restrict__ lut,
    vf4* __restrict__ out4,          // B*8 float4s
    int nsamp, long long total4, int nWaveTasks, int gridWaves)
{
    __shared__ float slut[37440];

    // Cooperative LDS fill: 9360 float4s (L3-resident after first blocks).
    {
        const vf4* src = (const vf4*)lut;
        vf4* dst = (vf4*)slut;
        for (int i = threadIdx.x; i < 9360; i += 1024) dst[i] = src[i];
    }
    __syncthreads();

    int t    = threadIdx.x;
    int lane = t & 63;
    int wave = t >> 6;                       // 0..15
    int gwave = blockIdx.x * 16 + wave;

    int s    = (lane & 7) >> 1;
    int half = lane & 1;
    unsigned mask  = (8u << (3 * s)) - 1u;                                  // 2^{3n}-1
    unsigned base4 = (unsigned)((0x0490009000100000ull >> (16 * s)) & 0xFFFFull); // {0,16,144,1168}
    const vf4* lutp = (const vf4*)slut + base4 + half;   // LDS-space pointer

    long long n4 = (long long)nsamp * 3;

    for (long long task = gwave; task < nWaveTasks; task += gridWaves) {
        long long waveS  = task * 64;        // first sample of this wave-task
        long long i4base = waveS * 3;

        // Coalesced input: 3 contiguous 64-lane int4 loads (1 KB each).
        unsigned m = 0;  // byte k = nibble of flat int4 (i4base + 64k + lane)
#pragma unroll
        for (int k = 0; k < 3; ++k) {
            long long idx = i4base + k * 64 + lane;
            if (idx < n4) {
                vi4 x = tb4[idx];
                unsigned nib = ((unsigned)x.x << 3) | ((unsigned)x.y << 2) |
                               ((unsigned)x.z << 1) |  (unsigned)x.w;
                m |= nib << (8 * k);
            }
        }

        // Reassemble this lane's 12-bit key from the 3 nibbles via shfl.
        unsigned P = 0;
#pragma unroll
        for (int j = 0; j < 3; ++j) {
            int f = 3 * lane + j;
            unsigned mm  = (unsigned)__shfl((int)m, f & 63, 64);
            unsigned nib = (mm >> (8 * (f >> 6))) & 0xFu;
            P |= nib << (8 - 4 * j);   // nib0<<8 | nib1<<4 | nib2
        }

        long long outBase = waveS * 8 + lane;
#pragma unroll
        for (int i = 0; i < 8; ++i) {
            unsigned Ps = (unsigned)__shfl((int)P, i * 8 + (lane >> 3), 64);
            long long g = outBase + (long long)(i * 64);
            if (g < total4) {
                vf4 v = lutp[(Ps & mask) * 2];     // ds_read_b128 from LDS
                __builtin_nontemporal_store(v, &out4[g]);
            }
        }
    }
}

extern "C" void kernel_launch(void* const* d_in, const int* in_sizes, int n_in,
                              void* d_out, int out_size, void* d_ws, size_t ws_size,
                              hipStream_t stream) {
    const int*   type_bits = (const int*)d_in[0];
    const float* pat       = (const float*)d_in[1];
    const float* pos       = (const float*)d_in[2];
    const int*   conn      = (const int*)d_in[3];
    float* lut = (float*)d_ws;   // needs 149,760 B

    int nsamp = in_sizes[0] / 12;                 // 2,000,000
    long long total4 = (long long)out_size / 4;   // 16,000,000 float4s
    int nWaveTasks = (nsamp + 63) / 64;           // 31250
    int nblocks    = 256;                         // 1 per CU (150 KB LDS each)
    int gridWaves  = nblocks * 16;

    build_lut_kernel<<<(4680 + 255) / 256, 256, 0, stream>>>(pat, pos, conn, lut);
    gather_kernel<<<nblocks, 1024, 0, stream>>>((const vi4*)type_bits, lut,
                                                (vf4*)d_out, nsamp, total4,
                                                nWaveTasks, gridWaves);
}